// Round 1
// baseline (1228.571 us; speedup 1.0000x reference)
//
#include <hip/hip_runtime.h>
#include <cstdint>

#define BATCH 64
#define SEQ   512
#define DIM   768
#define HEADS 12
#define KEEP  254      // index - 2
#define NOUT  256
#define KOTHER 257     // SEQ - index + 1

// ---------------- K1: partial column sums over atten ----------------
// grid = BATCH*HEADS*4 blocks (bh*4 + rowchunk), 128 threads, each thread
// owns 4 consecutive columns (float4), sums 128 rows. Fully coalesced,
// deterministic (no atomics).
__global__ void k1_colsum(const float* __restrict__ atten, float4* __restrict__ partial) {
    int bid = blockIdx.x;            // bh*4 + chunk
    int t   = threadIdx.x;           // 0..127
    int bh  = bid >> 2;
    int row0 = (bid & 3) << 7;       // chunk * 128
    const float4* A4 = (const float4*)(atten + (size_t)bh * SEQ * SEQ);
    const float4* p  = A4 + (size_t)row0 * (SEQ / 4) + t;
    float4 s = {0.f, 0.f, 0.f, 0.f};
#pragma unroll 8
    for (int r = 0; r < 128; ++r) {
        float4 v = p[(size_t)r * (SEQ / 4)];
        s.x += v.x; s.y += v.y; s.z += v.z; s.w += v.w;
    }
    partial[(size_t)bid * (SEQ / 4) + t] = s;
}

// ---------------- K2: reduce partials + subtract diagonal ----------------
// grid = BATCH blocks, SEQ threads. ab[b][j] = (colsum - diagsum)/12
__global__ void k2_reduce_diag(const float* __restrict__ partial,
                               const float* __restrict__ atten,
                               float* __restrict__ ab) {
    int b = blockIdx.x;
    int j = threadIdx.x;
    float s = 0.f;
#pragma unroll
    for (int c = 0; c < 48; ++c)
        s += partial[((size_t)(b * 48 + c)) * SEQ + j];
    float d = 0.f;
#pragma unroll
    for (int h = 0; h < HEADS; ++h)
        d += atten[((size_t)(b * HEADS + h)) * SEQ * SEQ + (size_t)j * (SEQ + 1)];
    ab[b * SEQ + j] = (s - d) / 12.0f;
}

// ---------------- K3: per-batch selection + softmax ----------------
// One block per batch, SEQ threads. Exact ranks with JAX top_k tie-break
// (value desc, index asc). keep set = ranks 0..253 among tokens 1..511;
// other set = complement (254+257 = 511 exactly).
__global__ void k3_select(const float* __restrict__ ab,
                          int* __restrict__ srcidx,
                          int* __restrict__ otheridx,
                          float* __restrict__ otherw) {
    __shared__ float sab[SEQ];
    __shared__ int   smask[SEQ];
    __shared__ float sred[SEQ];
    int b = blockIdx.x;
    int j = threadIdx.x;
    sab[j] = ab[b * SEQ + j];
    __syncthreads();
    float v = sab[j];
    int r = 0;
    if (j >= 1) {
        for (int k = 1; k < SEQ; ++k) {
            float u = sab[k];
            r += (u > v) || (u == v && k < j);
        }
    }
    int keep = (j >= 1) && (r < KEEP);
    smask[j] = keep;
    __syncthreads();
    // cnt = number of kept tokens with index < j (j>=1)
    int cnt = 0;
    for (int k = 1; k < j; ++k) cnt += smask[k];   // broadcast LDS reads
    // max over "other" set
    sred[j] = (j >= 1 && !keep) ? v : -3.4e38f;
    __syncthreads();
    for (int st = 256; st > 0; st >>= 1) {
        if (j < st) sred[j] = fmaxf(sred[j], sred[j + st]);
        __syncthreads();
    }
    float m = sred[0];
    __syncthreads();
    float e = (j >= 1 && !keep) ? expf(v - m) : 0.f;
    sred[j] = e;
    __syncthreads();
    for (int st = 256; st > 0; st >>= 1) {
        if (j < st) sred[j] += sred[j + st];
        __syncthreads();
    }
    float se = sred[0];
    if (j == 0) srcidx[b * NOUT] = 0;              // cls token always first
    if (j >= 1) {
        if (keep) {
            srcidx[b * NOUT + 1 + cnt] = j;        // positions 1..254, ascending j
        } else {
            int q = (j - 1) - cnt;                 // 0..256, ascending j
            otheridx[b * KOTHER + q] = j;
            otherw[b * KOTHER + q] = e / se;
        }
    }
}

// ---------------- K4: gather rows + weighted mean token ----------------
// grid = BATCH*NOUT blocks, 192 threads (768 floats = 192 float4/row)
__global__ void k4_out(const float* __restrict__ x,
                       const int* __restrict__ srcidx,
                       const int* __restrict__ otheridx,
                       const float* __restrict__ otherw,
                       float* __restrict__ out) {
    int blk = blockIdx.x;            // b*256 + p
    int b = blk >> 8;
    int p = blk & 255;
    int t = threadIdx.x;             // 0..191
    const float4* x4 = (const float4*)x;
    float4* o4 = (float4*)out;
    if (p < 255) {
        int j = srcidx[blk];
        o4[(size_t)blk * 192 + t] = x4[((size_t)b * SEQ + j) * 192 + t];
    } else {
        float4 acc = {0.f, 0.f, 0.f, 0.f};
        for (int q = 0; q < KOTHER; ++q) {
            int   j = otheridx[b * KOTHER + q];
            float w = otherw[b * KOTHER + q];
            float4 xv = x4[((size_t)b * SEQ + j) * 192 + t];
            acc.x += w * xv.x; acc.y += w * xv.y;
            acc.z += w * xv.z; acc.w += w * xv.w;
        }
        const float inv = 1.0f / 257.0f;           // mean over 257
        float4 o = {acc.x * inv, acc.y * inv, acc.z * inv, acc.w * inv};
        o4[(size_t)blk * 192 + t] = o;
    }
}

extern "C" void kernel_launch(void* const* d_in, const int* in_sizes, int n_in,
                              void* d_out, int out_size, void* d_ws, size_t ws_size,
                              hipStream_t stream) {
    const float* x     = (const float*)d_in[0];
    const float* atten = (const float*)d_in[1];
    float* out = (float*)d_out;
    char* ws = (char*)d_ws;

    // ws layout (all fully overwritten before read; no init needed)
    float* partial  = (float*)ws;                             // 3072*512*4 = 6291456 B
    float* ab       = (float*)(ws + 6291456);                 // 64*512*4   = 131072 B
    int*   srcidx   = (int*)(ws + 6291456 + 131072);          // 64*256*4   = 65536 B
    int*   otheridx = (int*)(ws + 6291456 + 131072 + 65536);  // 64*257*4   = 65792 B
    float* otherw   = (float*)(ws + 6291456 + 131072 + 65536 + 65792);

    k1_colsum<<<dim3(BATCH * HEADS * 4), dim3(128), 0, stream>>>(atten, (float4*)partial);
    k2_reduce_diag<<<dim3(BATCH), dim3(SEQ), 0, stream>>>(partial, atten, ab);
    k3_select<<<dim3(BATCH), dim3(SEQ), 0, stream>>>(ab, srcidx, otheridx, otherw);
    k4_out<<<dim3(BATCH * NOUT), dim3(192), 0, stream>>>(x, srcidx, otheridx, otherw, out);
}